// Round 5
// baseline (271.148 us; speedup 1.0000x reference)
//
#include <hip/hip_runtime.h>

#define NEGV -1.0e30f
#define CAP 128   // max in-edges per thread node; dataset mean 32, max ~65

__device__ __forceinline__ float rl(float v, int l) {
  return __int_as_float(__builtin_amdgcn_readlane(__float_as_int(v), l));
}

__device__ __forceinline__ void atomicMaxF(float* addr, float v) {
  if (v >= 0.0f) atomicMax((int*)addr, __float_as_int(v));
  else atomicMin((unsigned int*)addr, __float_as_uint(v));
}

// Per-node: thread mask; dense rank for thread nodes (atomic counter);
// batch id via ptr scan; init pooled[] to NEG; zero deg for own rank.
__global__ __launch_bounds__(256) void k_prep(
    const float* __restrict__ x, const int* __restrict__ ptr,
    int n, int nptr, int* __restrict__ mask, int* __restrict__ batch,
    int* __restrict__ rank, int* __restrict__ nodeof, int* __restrict__ deg,
    int* __restrict__ cnt, float* __restrict__ pooled, int npooled) {
  int i = blockIdx.x * blockDim.x + threadIdx.x;
  if (i < npooled) pooled[i] = NEGV;
  if (i >= n) return;
  const float* xr = x + (long long)i * 46;
  bool m = (xr[0] == 0.0f) && (xr[1] == 0.0f) && (xr[2] == 0.0f) &&
           (xr[3] == 0.0f) && (xr[4] == 1.0f);
  mask[i] = m ? 1 : 0;
  if (m) {
    int r = atomicAdd(cnt, 1);   // slot order irrelevant (sum/max commute)
    rank[i] = r;
    nodeof[r] = i;
    deg[r] = 0;
  }
  int b = 0;
  for (int g = 1; g < nptr; ++g)
    if (i >= ptr[g]) b = g;
  batch[i] = b;
}

// 4 edges per thread (int4 read of edge_index[1]); record edge id in its
// destination RANK's list. deg region (100KB) is L2-hot.
__global__ __launch_bounds__(256) void k_fill(
    const int* __restrict__ ei, const int* __restrict__ mask,
    const int* __restrict__ rank, int* __restrict__ deg,
    int* __restrict__ elist, long long E) {
  long long base = ((long long)blockIdx.x * blockDim.x + threadIdx.x) * 4;
  if (base >= E) return;
  int dst4[4];
  if (base + 4 <= E) {
    const int4 q = *(const int4*)(ei + E + base);
    dst4[0] = q.x; dst4[1] = q.y; dst4[2] = q.z; dst4[3] = q.w;
  } else {
    for (int j = 0; j < 4; ++j)
      dst4[j] = (base + j < E) ? ei[E + base + j] : -1;
  }
#pragma unroll
  for (int j = 0; j < 4; ++j) {
    const int dst = dst4[j];
    if (dst < 0 || (base + j >= E)) continue;
    if (mask[dst] == 0) continue;
    const int r = rank[dst];
    const int pos = atomicAdd(&deg[r], 1);
    if (pos < CAP) elist[(size_t)r * CAP + pos] = (int)(base + j);
  }
}

// FUSED gather + MLP + pool. One wave per thread-node rank (lane = feature).
// Gather-sum incoming edge rows (8 rows in flight), then the 64->128->128
// MLP via readlane broadcast (VALU work hides under HBM waits of other
// waves), then per-graph max via native int atomic-max trick.
__global__ __launch_bounds__(256) void k_gather_mlp(
    const float* __restrict__ ea, const int* __restrict__ nodeof,
    const int* __restrict__ deg, const int* __restrict__ elist,
    const int* __restrict__ cnt, const int* __restrict__ batch,
    const float* __restrict__ W1, const float* __restrict__ b1,
    const float* __restrict__ W2, const float* __restrict__ b2,
    float* __restrict__ pooled) {
  const int t = blockIdx.x * blockDim.x + threadIdx.x;
  const int wv = t >> 6;
  const int lane = t & 63;
  if (wv >= cnt[0]) return;
  const int node = nodeof[wv];
  int d = min(deg[wv], CAP);
  const int* el = elist + (size_t)wv * CAP;

  float acc = 0.0f;
  int k = 0;
  for (; k + 8 <= d; k += 8) {
    const int4 ia = *(const int4*)(el + k);       // 32B-aligned (k%8==0)
    const int4 ib = *(const int4*)(el + k + 4);
    const float v0 = ea[(long long)ia.x * 65 + lane];
    const float v1 = ea[(long long)ia.y * 65 + lane];
    const float v2 = ea[(long long)ia.z * 65 + lane];
    const float v3 = ea[(long long)ia.w * 65 + lane];
    const float v4 = ea[(long long)ib.x * 65 + lane];
    const float v5 = ea[(long long)ib.y * 65 + lane];
    const float v6 = ea[(long long)ib.z * 65 + lane];
    const float v7 = ea[(long long)ib.w * 65 + lane];
    acc += ((v0 + v1) + (v2 + v3)) + ((v4 + v5) + (v6 + v7));
  }
  for (; k < d; ++k) acc += ea[(long long)el[k] * 65 + lane];

  // h = relu(acc @ W1 + b1) @ W2 + b2   (W1: 64x128, W2: 128x128)
  float t0 = b1[lane], t1 = b1[64 + lane];
#pragma unroll 16
  for (int l = 0; l < 64; ++l) {
    const float av = rl(acc, l);
    t0 = fmaf(av, W1[l * 128 + lane], t0);
    t1 = fmaf(av, W1[l * 128 + 64 + lane], t1);
  }
  t0 = fmaxf(t0, 0.0f);
  t1 = fmaxf(t1, 0.0f);
  float h0 = b2[lane], h1 = b2[64 + lane];
#pragma unroll 16
  for (int m = 0; m < 64; ++m) {
    const float u = rl(t0, m);
    const float v = rl(t1, m);
    h0 = fmaf(u, W2[m * 128 + lane], h0);
    h1 = fmaf(u, W2[m * 128 + 64 + lane], h1);
    h0 = fmaf(v, W2[(64 + m) * 128 + lane], h0);
    h1 = fmaf(v, W2[(64 + m) * 128 + 64 + lane], h1);
  }

  const int b = batch[node];
  atomicMaxF(pooled + b * 128 + lane, h0);
  atomicMaxF(pooled + b * 128 + 64 + lane, h1);
}

// Tiny FFN: logits = relu(pooled @ Wf1 + bf1) @ Wf2 + bf2. One block.
__global__ __launch_bounds__(1024) void k_ffn(
    const float* __restrict__ pooled,
    const float* __restrict__ Wf1, const float* __restrict__ bf1,
    const float* __restrict__ Wf2, const float* __restrict__ bf2,
    float* __restrict__ out, int B) {
  __shared__ float hid[1024];
  int t = threadIdx.x;
  if (t < B * 64) {
    int g = t >> 6, j = t & 63;
    float acc = bf1[j];
    for (int k = 0; k < 128; ++k)
      acc = fmaf(pooled[g * 128 + k], Wf1[k * 64 + j], acc);
    hid[t] = fmaxf(acc, 0.0f);
  }
  __syncthreads();
  if (t < B * 2) {
    int g = t >> 1, c = t & 1;
    float acc = bf2[c];
    for (int j = 0; j < 64; ++j)
      acc = fmaf(hid[g * 64 + j], Wf2[j * 2 + c], acc);
    out[t] = acc;
  }
}

extern "C" void kernel_launch(void* const* d_in, const int* in_sizes, int n_in,
                              void* d_out, int out_size, void* d_ws, size_t ws_size,
                              hipStream_t stream) {
  const float* x = (const float*)d_in[0];
  const int* ei = (const int*)d_in[1];        // harness delivers ints as int32
  const float* ea = (const float*)d_in[2];
  const int* ptr = (const int*)d_in[3];       // int32
  const float* W1 = (const float*)d_in[4];
  const float* b1 = (const float*)d_in[5];
  const float* W2 = (const float*)d_in[6];
  const float* b2 = (const float*)d_in[7];
  const float* Wf1 = (const float*)d_in[8];
  const float* bf1 = (const float*)d_in[9];
  const float* Wf2 = (const float*)d_in[10];
  const float* bf2 = (const float*)d_in[11];

  const int n = in_sizes[0] / 46;
  const long long E = (long long)in_sizes[1] / 2;
  const int nptr = in_sizes[3];
  const int nB = nptr - 1;

  char* ws = (char*)d_ws;
  int* mask = (int*)ws;                                   // n i32
  int* batch = mask + n;                                  // n i32
  float* pooled = (float*)(batch + n);                    // nB*128 f32
  int* rank = (int*)(pooled + (size_t)nB * 128);          // n i32
  int* nodeof = rank + n;                                 // n i32
  int* deg = nodeof + n;                                  // n i32 (rank-idx)
  int* cnt = deg + n;                                     // 1 i32 (+pad)
  int* elist = cnt + 64;                                  // n*CAP i32 (rank-idx)

  hipMemsetAsync(cnt, 0, 4, stream);
  k_prep<<<(n + 255) / 256, 256, 0, stream>>>(x, ptr, n, nptr, mask, batch,
                                              rank, nodeof, deg, cnt,
                                              pooled, nB * 128);
  k_fill<<<(int)((E + 1023) / 1024), 256, 0, stream>>>(ei, mask, rank, deg,
                                                       elist, E);
  k_gather_mlp<<<(n * 64 + 255) / 256, 256, 0, stream>>>(
      ea, nodeof, deg, elist, cnt, batch, W1, b1, W2, b2, pooled);
  k_ffn<<<1, 1024, 0, stream>>>(pooled, Wf1, bf1, Wf2, bf2, (float*)d_out, nB);
}

// Round 6
// 199.936 us; speedup vs baseline: 1.3562x; 1.3562x over previous
//
#include <hip/hip_runtime.h>

#define NEGV -1.0e30f
#define CAP 128   // max in-edges per thread node; dataset mean 32, max ~65

struct __attribute__((packed, aligned(4))) F4 { float x, y, z, w; };

__device__ __forceinline__ float rl(float v, int l) {
  return __int_as_float(__builtin_amdgcn_readlane(__float_as_int(v), l));
}

__device__ __forceinline__ void atomicMaxF(float* addr, float v) {
  if (v >= 0.0f) atomicMax((int*)addr, __float_as_int(v));
  else atomicMin((unsigned int*)addr, __float_as_uint(v));
}

// Per-node: thread mask; dense rank for thread nodes (atomic counter);
// batch id via ptr scan; init pooled[] to NEG; zero deg for own rank.
__global__ __launch_bounds__(256) void k_prep(
    const float* __restrict__ x, const int* __restrict__ ptr,
    int n, int nptr, int* __restrict__ mask, int* __restrict__ batch,
    int* __restrict__ rank, int* __restrict__ nodeof, int* __restrict__ deg,
    int* __restrict__ cnt, float* __restrict__ pooled, int npooled) {
  int i = blockIdx.x * blockDim.x + threadIdx.x;
  if (i < npooled) pooled[i] = NEGV;
  if (i >= n) return;
  const float* xr = x + (long long)i * 46;
  bool m = (xr[0] == 0.0f) && (xr[1] == 0.0f) && (xr[2] == 0.0f) &&
           (xr[3] == 0.0f) && (xr[4] == 1.0f);
  mask[i] = m ? 1 : 0;
  if (m) {
    int r = atomicAdd(cnt, 1);   // slot order irrelevant (sum/max commute)
    rank[i] = r;
    nodeof[r] = i;
    deg[r] = 0;
  }
  int b = 0;
  for (int g = 1; g < nptr; ++g)
    if (i >= ptr[g]) b = g;
  batch[i] = b;
}

// 4 edges per thread (int4 read of edge_index[1]); record edge id in its
// destination RANK's list. deg region (100KB) is L2-hot.
__global__ __launch_bounds__(256) void k_fill(
    const int* __restrict__ ei, const int* __restrict__ mask,
    const int* __restrict__ rank, int* __restrict__ deg,
    int* __restrict__ elist, long long E) {
  long long base = ((long long)blockIdx.x * blockDim.x + threadIdx.x) * 4;
  if (base >= E) return;
  int dst4[4];
  if (base + 4 <= E) {
    const int4 q = *(const int4*)(ei + E + base);
    dst4[0] = q.x; dst4[1] = q.y; dst4[2] = q.z; dst4[3] = q.w;
  } else {
    for (int j = 0; j < 4; ++j)
      dst4[j] = (base + j < E) ? ei[E + base + j] : -1;
  }
#pragma unroll
  for (int j = 0; j < 4; ++j) {
    const int dst = dst4[j];
    if (dst < 0 || (base + j >= E)) continue;
    if (mask[dst] == 0) continue;
    const int r = rank[dst];
    const int pos = atomicAdd(&deg[r], 1);
    if (pos < CAP) elist[(size_t)r * CAP + pos] = (int)(base + j);
  }
}

// Wide gather: one wave per thread-node rank; 4x16-lane groups, each group
// reads one edge row as 16 x float4 (one 1KB VMEM op covers 4 rows).
// 8 rows in flight per iteration. Cross-group shfl_xor reduce, float4 store.
__global__ __launch_bounds__(256) void k_gather(
    const float* __restrict__ ea, const int* __restrict__ nodeof,
    const int* __restrict__ deg, const int* __restrict__ elist,
    const int* __restrict__ cnt, float* __restrict__ agg) {
  const int t = blockIdx.x * blockDim.x + threadIdx.x;
  const int wv = t >> 6;
  const int lane = t & 63;
  if (wv >= cnt[0]) return;
  const int node = nodeof[wv];
  const int d = min(deg[wv], CAP);
  const int* el = elist + (size_t)wv * CAP;
  const int g = lane >> 4;         // edge slot within the 4/8-row batch
  const int sub = lane & 15;       // covers features 4*sub .. 4*sub+3

  float ax = 0.f, ay = 0.f, az = 0.f, aw = 0.f;
  float bx = 0.f, by = 0.f, bz = 0.f, bw = 0.f;
  for (int k = 0; k < d; k += 8) {
    const int ka = k + g, kb = k + 4 + g;
    const long long eA = el[ka < d ? ka : d - 1];
    const long long eB = el[kb < d ? kb : d - 1];
    F4 va = *(const F4*)(ea + eA * 65 + sub * 4);
    F4 vb = *(const F4*)(ea + eB * 65 + sub * 4);
    if (ka < d) { ax += va.x; ay += va.y; az += va.z; aw += va.w; }
    if (kb < d) { bx += vb.x; by += vb.y; bz += vb.z; bw += vb.w; }
  }
  ax += bx; ay += by; az += bz; aw += bw;
  ax += __shfl_xor(ax, 32); ay += __shfl_xor(ay, 32);
  az += __shfl_xor(az, 32); aw += __shfl_xor(aw, 32);
  ax += __shfl_xor(ax, 16); ay += __shfl_xor(ay, 16);
  az += __shfl_xor(az, 16); aw += __shfl_xor(aw, 16);
  if (g == 0) {
    float4 s; s.x = ax; s.y = ay; s.z = az; s.w = aw;
    *(float4*)(agg + (size_t)node * 64 + sub * 4) = s;
  }
}

// Wave per 16-node chunk. Gather thread nodes, MLP 4 nodes jointly
// (W1/W2 loads amortized 4x), readlane-broadcast dot products,
// running per-graph max, flush via float atomicMax trick.
__global__ __launch_bounds__(256) void k_mlp(
    const float* __restrict__ agg, const int* __restrict__ mask,
    const int* __restrict__ batch,
    const float* __restrict__ W1, const float* __restrict__ b1,
    const float* __restrict__ W2, const float* __restrict__ b2,
    float* __restrict__ pooled, int n) {
  const int lane = threadIdx.x & 63;
  const int wv = blockIdx.x * 4 + (threadIdx.x >> 6);
  const int n0 = wv * 16;
  if (n0 >= n) return;
  const int cnt = min(16, n - n0);
  int mv = 0, bvv = 0;
  if (lane < cnt) {
    mv = mask[n0 + lane];
    bvv = batch[n0 + lane];
  }
  unsigned long long bal = __ballot(mv != 0);
  unsigned mb = (unsigned)(bal & 0xFFFFull);
  if (mb == 0) return;

  const float bias1a = b1[lane], bias1b = b1[64 + lane];
  const float bias2a = b2[lane], bias2b = b2[64 + lane];
  float m0 = NEGV, m1 = NEGV;
  int cur = -1;

  while (mb) {
    int nd[4];
    int lastid = 0;
#pragma unroll
    for (int s = 0; s < 4; ++s) {   // extract up to 4 node ids; pad w/ repeat
      if (mb) { lastid = __ffs(mb) - 1; mb &= mb - 1; }
      nd[s] = lastid;               // duplicates are harmless for max-pool
    }
    float a[4], t0[4], t1[4];
#pragma unroll
    for (int s = 0; s < 4; ++s) {
      a[s] = agg[(size_t)(n0 + nd[s]) * 64 + lane];
      t0[s] = bias1a;
      t1[s] = bias1b;
    }
#pragma unroll 16
    for (int l = 0; l < 64; ++l) {
      const float w0 = W1[l * 128 + lane];
      const float w1 = W1[l * 128 + 64 + lane];
#pragma unroll
      for (int s = 0; s < 4; ++s) {
        const float av = rl(a[s], l);
        t0[s] = fmaf(av, w0, t0[s]);
        t1[s] = fmaf(av, w1, t1[s]);
      }
    }
    float h0[4], h1[4];
#pragma unroll
    for (int s = 0; s < 4; ++s) {
      t0[s] = fmaxf(t0[s], 0.0f);
      t1[s] = fmaxf(t1[s], 0.0f);
      h0[s] = bias2a;
      h1[s] = bias2b;
    }
#pragma unroll 16
    for (int j = 0; j < 64; ++j) {
      const float w0 = W2[j * 128 + lane];
      const float w1 = W2[j * 128 + 64 + lane];
      const float w2 = W2[(64 + j) * 128 + lane];
      const float w3 = W2[(64 + j) * 128 + 64 + lane];
#pragma unroll
      for (int s = 0; s < 4; ++s) {
        const float u = rl(t0[s], j);
        const float v = rl(t1[s], j);
        h0[s] = fmaf(u, w0, h0[s]);
        h1[s] = fmaf(u, w1, h1[s]);
        h0[s] = fmaf(v, w2, h0[s]);
        h1[s] = fmaf(v, w3, h1[s]);
      }
    }
#pragma unroll
    for (int s = 0; s < 4; ++s) {
      const int bb = __builtin_amdgcn_readlane(bvv, nd[s]);
      if (bb != cur) {
        if (cur >= 0) {
          atomicMaxF(pooled + cur * 128 + lane, m0);
          atomicMaxF(pooled + cur * 128 + 64 + lane, m1);
        }
        cur = bb;
        m0 = NEGV;
        m1 = NEGV;
      }
      m0 = fmaxf(m0, h0[s]);
      m1 = fmaxf(m1, h1[s]);
    }
  }
  if (cur >= 0) {
    atomicMaxF(pooled + cur * 128 + lane, m0);
    atomicMaxF(pooled + cur * 128 + 64 + lane, m1);
  }
}

// Tiny FFN: logits = relu(pooled @ Wf1 + bf1) @ Wf2 + bf2. One block.
__global__ __launch_bounds__(1024) void k_ffn(
    const float* __restrict__ pooled,
    const float* __restrict__ Wf1, const float* __restrict__ bf1,
    const float* __restrict__ Wf2, const float* __restrict__ bf2,
    float* __restrict__ out, int B) {
  __shared__ float hid[1024];
  int t = threadIdx.x;
  if (t < B * 64) {
    int g = t >> 6, j = t & 63;
    float acc = bf1[j];
    for (int k = 0; k < 128; ++k)
      acc = fmaf(pooled[g * 128 + k], Wf1[k * 64 + j], acc);
    hid[t] = fmaxf(acc, 0.0f);
  }
  __syncthreads();
  if (t < B * 2) {
    int g = t >> 1, c = t & 1;
    float acc = bf2[c];
    for (int j = 0; j < 64; ++j)
      acc = fmaf(hid[g * 64 + j], Wf2[j * 2 + c], acc);
    out[t] = acc;
  }
}

extern "C" void kernel_launch(void* const* d_in, const int* in_sizes, int n_in,
                              void* d_out, int out_size, void* d_ws, size_t ws_size,
                              hipStream_t stream) {
  const float* x = (const float*)d_in[0];
  const int* ei = (const int*)d_in[1];        // harness delivers ints as int32
  const float* ea = (const float*)d_in[2];
  const int* ptr = (const int*)d_in[3];       // int32
  const float* W1 = (const float*)d_in[4];
  const float* b1 = (const float*)d_in[5];
  const float* W2 = (const float*)d_in[6];
  const float* b2 = (const float*)d_in[7];
  const float* Wf1 = (const float*)d_in[8];
  const float* bf1 = (const float*)d_in[9];
  const float* Wf2 = (const float*)d_in[10];
  const float* bf2 = (const float*)d_in[11];

  const int n = in_sizes[0] / 46;
  const long long E = (long long)in_sizes[1] / 2;
  const int nptr = in_sizes[3];
  const int nB = nptr - 1;

  char* ws = (char*)d_ws;
  float* agg = (float*)ws;                                // n*64 f32
  int* mask = (int*)(ws + (size_t)n * 64 * 4);            // n i32
  int* batch = mask + n;                                  // n i32
  float* pooled = (float*)(batch + n);                    // nB*128 f32
  int* rank = (int*)(pooled + (size_t)nB * 128);          // n i32
  int* nodeof = rank + n;                                 // n i32
  int* deg = nodeof + n;                                  // n i32 (rank-idx)
  int* cnt = deg + n;                                     // 1 i32 (+pad)
  int* elist = cnt + 64;                                  // n*CAP i32 (rank-idx)

  hipMemsetAsync(cnt, 0, 4, stream);
  k_prep<<<(n + 255) / 256, 256, 0, stream>>>(x, ptr, n, nptr, mask, batch,
                                              rank, nodeof, deg, cnt,
                                              pooled, nB * 128);
  k_fill<<<(int)((E + 1023) / 1024), 256, 0, stream>>>(ei, mask, rank, deg,
                                                       elist, E);
  k_gather<<<(n * 64 + 255) / 256, 256, 0, stream>>>(ea, nodeof, deg, elist,
                                                     cnt, agg);
  const int waves = (n + 15) / 16;
  k_mlp<<<(waves + 3) / 4, 256, 0, stream>>>(agg, mask, batch, W1, b1, W2, b2,
                                             pooled, n);
  k_ffn<<<1, 1024, 0, stream>>>(pooled, Wf1, bf1, Wf2, bf2, (float*)d_out, nB);
}

// Round 7
// 188.868 us; speedup vs baseline: 1.4356x; 1.0586x over previous
//
#include <hip/hip_runtime.h>

#define NEGV -1.0e30f
#define CAP 128   // max in-edges per thread node; dataset mean 32, max ~65

struct __attribute__((packed, aligned(4))) F4 { float x, y, z, w; };

__device__ __forceinline__ float rl(float v, int l) {
  return __int_as_float(__builtin_amdgcn_readlane(__float_as_int(v), l));
}

__device__ __forceinline__ void atomicMaxF(float* addr, float v) {
  if (v >= 0.0f) atomicMax((int*)addr, __float_as_int(v));
  else atomicMin((unsigned int*)addr, __float_as_uint(v));
}

// Per-node: thread mask (x[:,4]==1 discriminates the two one-hot patterns);
// dense rank for thread nodes; batch via ptr scan; init pooled to NEG.
__global__ __launch_bounds__(256) void k_prep(
    const float* __restrict__ x, const int* __restrict__ ptr,
    int n, int nptr, int* __restrict__ mask, int* __restrict__ batch,
    int* __restrict__ rank, int* __restrict__ nodeof, int* __restrict__ deg,
    int* __restrict__ cnt, float* __restrict__ pooled, int npooled) {
  int i = blockIdx.x * blockDim.x + threadIdx.x;
  if (i < npooled) pooled[i] = NEGV;
  if (i >= n) return;
  bool m = (x[(long long)i * 46 + 4] == 1.0f);
  mask[i] = m ? 1 : 0;
  if (m) {
    int r = atomicAdd(cnt, 1);   // slot order irrelevant (sum/max commute)
    rank[i] = r;
    nodeof[r] = i;
    deg[r] = 0;
  }
  int b = 0;
  for (int g = 1; g < nptr; ++g)
    if (i >= ptr[g]) b = g;
  batch[i] = b;
}

// 4 edges per thread (int4 read of edge_index[1]); record edge id in its
// destination RANK's list. deg region (100KB) is L2-hot.
__global__ __launch_bounds__(256) void k_fill(
    const int* __restrict__ ei, const int* __restrict__ mask,
    const int* __restrict__ rank, int* __restrict__ deg,
    int* __restrict__ elist, long long E) {
  long long base = ((long long)blockIdx.x * blockDim.x + threadIdx.x) * 4;
  if (base >= E) return;
  int dst4[4];
  if (base + 4 <= E) {
    const int4 q = *(const int4*)(ei + E + base);
    dst4[0] = q.x; dst4[1] = q.y; dst4[2] = q.z; dst4[3] = q.w;
  } else {
    for (int j = 0; j < 4; ++j)
      dst4[j] = (base + j < E) ? ei[E + base + j] : -1;
  }
#pragma unroll
  for (int j = 0; j < 4; ++j) {
    const int dst = dst4[j];
    if (dst < 0 || (base + j >= E)) continue;
    if (mask[dst] == 0) continue;
    const int r = rank[dst];
    const int pos = atomicAdd(&deg[r], 1);
    if (pos < CAP) elist[(size_t)r * CAP + pos] = (int)(base + j);
  }
}

// Wide gather, 16 rows in flight: one wave per thread-node rank; 4x16-lane
// groups, each group reads 4 edge rows as 16 x float4 per row. Cross-group
// shfl_xor reduce, float4 store.
__global__ __launch_bounds__(256) void k_gather(
    const float* __restrict__ ea, const int* __restrict__ nodeof,
    const int* __restrict__ deg, const int* __restrict__ elist,
    const int* __restrict__ cnt, float* __restrict__ agg) {
  const int t = blockIdx.x * blockDim.x + threadIdx.x;
  const int wv = t >> 6;
  const int lane = t & 63;
  if (wv >= cnt[0]) return;
  const int node = nodeof[wv];
  const int d = min(deg[wv], CAP);
  const int* el = elist + (size_t)wv * CAP;
  const int g = lane >> 4;         // edge slot within the 16-row batch
  const int sub = lane & 15;       // covers features 4*sub .. 4*sub+3

  float a0x = 0.f, a0y = 0.f, a0z = 0.f, a0w = 0.f;
  float a1x = 0.f, a1y = 0.f, a1z = 0.f, a1w = 0.f;
  float a2x = 0.f, a2y = 0.f, a2z = 0.f, a2w = 0.f;
  float a3x = 0.f, a3y = 0.f, a3z = 0.f, a3w = 0.f;
  for (int k = 0; k < d; k += 16) {
    const int i0 = k + g, i1 = k + 4 + g, i2 = k + 8 + g, i3 = k + 12 + g;
    const long long e0 = el[i0 < d ? i0 : d - 1];
    const long long e1 = el[i1 < d ? i1 : d - 1];
    const long long e2 = el[i2 < d ? i2 : d - 1];
    const long long e3 = el[i3 < d ? i3 : d - 1];
    const F4 v0 = *(const F4*)(ea + e0 * 65 + sub * 4);
    const F4 v1 = *(const F4*)(ea + e1 * 65 + sub * 4);
    const F4 v2 = *(const F4*)(ea + e2 * 65 + sub * 4);
    const F4 v3 = *(const F4*)(ea + e3 * 65 + sub * 4);
    if (i0 < d) { a0x += v0.x; a0y += v0.y; a0z += v0.z; a0w += v0.w; }
    if (i1 < d) { a1x += v1.x; a1y += v1.y; a1z += v1.z; a1w += v1.w; }
    if (i2 < d) { a2x += v2.x; a2y += v2.y; a2z += v2.z; a2w += v2.w; }
    if (i3 < d) { a3x += v3.x; a3y += v3.y; a3z += v3.z; a3w += v3.w; }
  }
  float ax = (a0x + a1x) + (a2x + a3x);
  float ay = (a0y + a1y) + (a2y + a3y);
  float az = (a0z + a1z) + (a2z + a3z);
  float aw = (a0w + a1w) + (a2w + a3w);
  ax += __shfl_xor(ax, 32); ay += __shfl_xor(ay, 32);
  az += __shfl_xor(az, 32); aw += __shfl_xor(aw, 32);
  ax += __shfl_xor(ax, 16); ay += __shfl_xor(ay, 16);
  az += __shfl_xor(az, 16); aw += __shfl_xor(aw, 16);
  if (g == 0) {
    float4 s; s.x = ax; s.y = ay; s.z = az; s.w = aw;
    *(float4*)(agg + (size_t)node * 64 + sub * 4) = s;
  }
}

// 16 waves per block share an LDS-staged W2 (64KB). Each wave: 16-node chunk,
// MLP 4 nodes jointly (W1 via L1 - it is exactly L1-sized), readlane
// broadcasts, per-graph running max, float atomicMax flush.
__global__ __launch_bounds__(1024) void k_mlp(
    const float* __restrict__ agg, const int* __restrict__ mask,
    const int* __restrict__ batch,
    const float* __restrict__ W1, const float* __restrict__ b1,
    const float* __restrict__ W2, const float* __restrict__ b2,
    float* __restrict__ pooled, int n) {
  __shared__ float sW2[128 * 128];
  {
    const float4* src = (const float4*)W2;
    float4* dst = (float4*)sW2;
    for (int i = threadIdx.x; i < 128 * 128 / 4; i += 1024) dst[i] = src[i];
  }
  __syncthreads();

  const int lane = threadIdx.x & 63;
  const int wv = blockIdx.x * 16 + (threadIdx.x >> 6);
  const int n0 = wv * 16;
  if (n0 >= n) return;
  const int cnt = min(16, n - n0);
  int mv = 0, bvv = 0;
  if (lane < cnt) {
    mv = mask[n0 + lane];
    bvv = batch[n0 + lane];
  }
  unsigned long long bal = __ballot(mv != 0);
  unsigned mb = (unsigned)(bal & 0xFFFFull);
  if (mb == 0) return;

  const float bias1a = b1[lane], bias1b = b1[64 + lane];
  const float bias2a = b2[lane], bias2b = b2[64 + lane];
  float m0 = NEGV, m1 = NEGV;
  int cur = -1;

  while (mb) {
    int nd[4];
    int lastid = 0;
#pragma unroll
    for (int s = 0; s < 4; ++s) {   // extract up to 4 node ids; pad w/ repeat
      if (mb) { lastid = __ffs(mb) - 1; mb &= mb - 1; }
      nd[s] = lastid;               // duplicates are harmless for max-pool
    }
    float a[4], t0[4], t1[4];
#pragma unroll
    for (int s = 0; s < 4; ++s) {
      a[s] = agg[(size_t)(n0 + nd[s]) * 64 + lane];
      t0[s] = bias1a;
      t1[s] = bias1b;
    }
#pragma unroll 16
    for (int l = 0; l < 64; ++l) {
      const float w0 = W1[l * 128 + lane];
      const float w1 = W1[l * 128 + 64 + lane];
#pragma unroll
      for (int s = 0; s < 4; ++s) {
        const float av = rl(a[s], l);
        t0[s] = fmaf(av, w0, t0[s]);
        t1[s] = fmaf(av, w1, t1[s]);
      }
    }
    float h0[4], h1[4];
#pragma unroll
    for (int s = 0; s < 4; ++s) {
      t0[s] = fmaxf(t0[s], 0.0f);
      t1[s] = fmaxf(t1[s], 0.0f);
      h0[s] = bias2a;
      h1[s] = bias2b;
    }
#pragma unroll 16
    for (int j = 0; j < 64; ++j) {
      const float w0 = sW2[j * 128 + lane];
      const float w1 = sW2[j * 128 + 64 + lane];
      const float w2 = sW2[(64 + j) * 128 + lane];
      const float w3 = sW2[(64 + j) * 128 + 64 + lane];
#pragma unroll
      for (int s = 0; s < 4; ++s) {
        const float u = rl(t0[s], j);
        const float v = rl(t1[s], j);
        h0[s] = fmaf(u, w0, h0[s]);
        h1[s] = fmaf(u, w1, h1[s]);
        h0[s] = fmaf(v, w2, h0[s]);
        h1[s] = fmaf(v, w3, h1[s]);
      }
    }
#pragma unroll
    for (int s = 0; s < 4; ++s) {
      const int bb = __builtin_amdgcn_readlane(bvv, nd[s]);
      if (bb != cur) {
        if (cur >= 0) {
          atomicMaxF(pooled + cur * 128 + lane, m0);
          atomicMaxF(pooled + cur * 128 + 64 + lane, m1);
        }
        cur = bb;
        m0 = NEGV;
        m1 = NEGV;
      }
      m0 = fmaxf(m0, h0[s]);
      m1 = fmaxf(m1, h1[s]);
    }
  }
  if (cur >= 0) {
    atomicMaxF(pooled + cur * 128 + lane, m0);
    atomicMaxF(pooled + cur * 128 + 64 + lane, m1);
  }
}

// Tiny FFN: logits = relu(pooled @ Wf1 + bf1) @ Wf2 + bf2. One block.
__global__ __launch_bounds__(1024) void k_ffn(
    const float* __restrict__ pooled,
    const float* __restrict__ Wf1, const float* __restrict__ bf1,
    const float* __restrict__ Wf2, const float* __restrict__ bf2,
    float* __restrict__ out, int B) {
  __shared__ float hid[1024];
  int t = threadIdx.x;
  if (t < B * 64) {
    int g = t >> 6, j = t & 63;
    float acc = bf1[j];
    for (int k = 0; k < 128; ++k)
      acc = fmaf(pooled[g * 128 + k], Wf1[k * 64 + j], acc);
    hid[t] = fmaxf(acc, 0.0f);
  }
  __syncthreads();
  if (t < B * 2) {
    int g = t >> 1, c = t & 1;
    float acc = bf2[c];
    for (int j = 0; j < 64; ++j)
      acc = fmaf(hid[g * 64 + j], Wf2[j * 2 + c], acc);
    out[t] = acc;
  }
}

extern "C" void kernel_launch(void* const* d_in, const int* in_sizes, int n_in,
                              void* d_out, int out_size, void* d_ws, size_t ws_size,
                              hipStream_t stream) {
  const float* x = (const float*)d_in[0];
  const int* ei = (const int*)d_in[1];        // harness delivers ints as int32
  const float* ea = (const float*)d_in[2];
  const int* ptr = (const int*)d_in[3];       // int32
  const float* W1 = (const float*)d_in[4];
  const float* b1 = (const float*)d_in[5];
  const float* W2 = (const float*)d_in[6];
  const float* b2 = (const float*)d_in[7];
  const float* Wf1 = (const float*)d_in[8];
  const float* bf1 = (const float*)d_in[9];
  const float* Wf2 = (const float*)d_in[10];
  const float* bf2 = (const float*)d_in[11];

  const int n = in_sizes[0] / 46;
  const long long E = (long long)in_sizes[1] / 2;
  const int nptr = in_sizes[3];
  const int nB = nptr - 1;

  char* ws = (char*)d_ws;
  float* agg = (float*)ws;                                // n*64 f32
  int* mask = (int*)(ws + (size_t)n * 64 * 4);            // n i32
  int* batch = mask + n;                                  // n i32
  float* pooled = (float*)(batch + n);                    // nB*128 f32
  int* rank = (int*)(pooled + (size_t)nB * 128);          // n i32
  int* nodeof = rank + n;                                 // n i32
  int* deg = nodeof + n;                                  // n i32 (rank-idx)
  int* cnt = deg + n;                                     // 1 i32 (+pad)
  int* elist = cnt + 64;                                  // n*CAP i32 (rank-idx)

  hipMemsetAsync(cnt, 0, 4, stream);
  k_prep<<<(n + 255) / 256, 256, 0, stream>>>(x, ptr, n, nptr, mask, batch,
                                              rank, nodeof, deg, cnt,
                                              pooled, nB * 128);
  k_fill<<<(int)((E + 1023) / 1024), 256, 0, stream>>>(ei, mask, rank, deg,
                                                       elist, E);
  k_gather<<<(n * 64 + 255) / 256, 256, 0, stream>>>(ea, nodeof, deg, elist,
                                                     cnt, agg);
  const int chunkwaves = (n + 15) / 16;
  k_mlp<<<(chunkwaves + 15) / 16, 1024, 0, stream>>>(agg, mask, batch, W1, b1,
                                                     W2, b2, pooled, n);
  k_ffn<<<1, 1024, 0, stream>>>(pooled, Wf1, bf1, Wf2, bf2, (float*)d_out, nB);
}